// Round 5
// baseline (463.374 us; speedup 1.0000x reference)
//
#include <hip/hip_runtime.h>

// MoE forward: shared SwiGLU expert + top-2/8 routed SwiGLU experts + aux loss.
// bf16 MFMA (16x16x32) GEMMs, 128-tile, global_load_lds width-16 staging.
// R1: atomic-free routing. R2: XOR chunk swizzle (0 LDS bank conflicts).
// R3/R4: dbuf LDS + raw s_barrier + vmcnt(8), XCD-aware tile remap.
// R5: fuse 4 GEMM stages -> 2 launches (shared+routed co-resident), f32
// unsafeAtomicAdd combine into zeroed out (rout buffer eliminated), router
// parallelism 2x.

typedef unsigned short u16;
typedef unsigned int   u32;
typedef short short8 __attribute__((ext_vector_type(8)));
typedef float f32x4  __attribute__((ext_vector_type(4)));

#define AS1 __attribute__((address_space(1)))
#define AS3 __attribute__((address_space(3)))

constexpr int T  = 8192;
constexpr int H  = 1024;
constexpr int E  = 8;
constexpr int D  = 512;
constexpr int DS = 1024;          // shared expert width
constexpr int PAIR_CAP  = 17408;  // 136 * 128 >= 16384 + 8*127
constexpr int MT_ROUTED = 136;    // routed m-tiles (128 rows each)
constexpr int RB = 512;           // router blocks (16 tokens each)

// grid splits for fused kernels
constexpr int GU_ROUTED_BLKS = 8 * MT_ROUTED;   // 1088 (N=512 -> 8 n-tiles)
constexpr int GU_SHARED_BLKS = 16 * (T / 128);  // 1024 (N=1024 -> 16 n-tiles)
constexpr int DN_SHARED_BLKS = 8 * (T / 128);   // 512
constexpr int DN_ROUTED_BLKS = 8 * MT_ROUTED;   // 1088

__device__ __forceinline__ u16 f2bf(float f){
  u32 u = __builtin_bit_cast(u32, f);
  u += 0x7fffu + ((u >> 16) & 1u);   // round-to-nearest-even
  return (u16)(u >> 16);
}

// async global->LDS, 16B per lane. LDS dest = wave-uniform base + lane*16.
__device__ __forceinline__ void gl_lds16(const u16* g, u16* l){
  __builtin_amdgcn_global_load_lds((const AS1 void*)g, (AS3 void*)l, 16, 0, 0);
}

// s_waitcnt imm: vm[3:0] | exp=7<<4 | lgkm=15<<8 (vmcnt high bits 0)
__device__ __forceinline__ void wait_vmcnt8(){ __builtin_amdgcn_s_waitcnt(0x0f78); }
__device__ __forceinline__ void wait_vmcnt0(){ __builtin_amdgcn_s_waitcnt(0x0f70); }

// workgroup barrier with LDS-only ordering (no global vmcnt drain)
__device__ __forceinline__ void bar_sync(){
  __builtin_amdgcn_fence(__ATOMIC_RELEASE, "workgroup", "local");
  __builtin_amdgcn_s_barrier();
  __builtin_amdgcn_fence(__ATOMIC_ACQUIRE, "workgroup", "local");
}

// Per-wave staging pointers for a ROWS x 64(bf16) tile, XOR-swizzled:
// LDS slot (row, ch) holds global chunk (ch ^ (row&7)); swizzle applied on the
// per-lane GLOBAL source address (LDS dest must stay lane-ordered for
// global_load_lds). Row pointers precomputed once (gather loads hoisted).
template<int ISS>
struct StagePtr { const u16* p[ISS]; };

template<int ROWS>
__device__ __forceinline__ void stage_init(StagePtr<ROWS/32>& sp,
    const u16* __restrict__ gbase, int ld, int rowbase,
    const int* __restrict__ gather, int wave, int lane){
  constexpr int ISS = ROWS / 32;
  int lr = lane >> 3, ch = lane & 7;
  int chs = (ch ^ lr) * 8;         // swizzled source chunk offset (elems)
#pragma unroll
  for (int j = 0; j < ISS; ++j){
    int idx = wave * ISS + j;
    int row = idx * 8 + lr;
    int grow = gather ? gather[rowbase + row] : (rowbase + row);
    sp.p[j] = gbase + (long)grow * ld + chs;
  }
}

template<int ROWS>
__device__ __forceinline__ void stage_issue(const StagePtr<ROWS/32>& sp, int k0,
                                            u16* lds, int wave, int lane){
  constexpr int ISS = ROWS / 32;
#pragma unroll
  for (int j = 0; j < ISS; ++j)
    gl_lds16(sp.p[j] + k0, lds + (wave * ISS + j) * 512);
}

// Fragment read offset (elems) for logical chunk c at a row with row&7==lane&7.
__device__ __forceinline__ int swz_off(int c, int lane){
  return ((c ^ (lane & 7)) * 8);
}

// ---------------- router: logits -> softmax -> top2 + bf16 convert of x -----
// 512 blocks x 4 waves x 4 tokens. No global atomics. Also writes xb (bf16).
__global__ void __launch_bounds__(256) router_kernel(
    const float* __restrict__ x, const float* __restrict__ Wr,
    u16* __restrict__ xb,
    int* __restrict__ topk_idx, float* __restrict__ topk_w,
    int* __restrict__ partial_hist, float* __restrict__ partial_probs)
{
  __shared__ int   hist_s[4][8];
  __shared__ float ps_s[4][8];
  int tid = threadIdx.x, lane = tid & 63, wv = tid >> 6;
  int   histl[8] = {0,0,0,0,0,0,0,0};
  float psl[8]   = {0.f,0.f,0.f,0.f,0.f,0.f,0.f,0.f};

  for (int it = 0; it < 4; ++it){
    int t = blockIdx.x * 16 + wv * 4 + it;
    const float4* xr = (const float4*)(x + (long)t * H);
    uint2* xbr = (uint2*)(xb + (long)t * H);
    float acc[8];
#pragma unroll
    for (int e = 0; e < 8; ++e) acc[e] = 0.f;
#pragma unroll
    for (int i = 0; i < 4; ++i){
      float4 xv = xr[i * 64 + lane];
      u32 lo = (u32)f2bf(xv.x) | ((u32)f2bf(xv.y) << 16);
      u32 hi = (u32)f2bf(xv.z) | ((u32)f2bf(xv.w) << 16);
      xbr[i * 64 + lane] = make_uint2(lo, hi);
      int h0 = i * 256 + lane * 4;
#pragma unroll
      for (int j = 0; j < 4; ++j){
        float xs = (j == 0) ? xv.x : (j == 1) ? xv.y : (j == 2) ? xv.z : xv.w;
        const float4* wr = (const float4*)(Wr + (long)(h0 + j) * E);
        float4 w0 = wr[0], w1 = wr[1];
        acc[0] += xs * w0.x; acc[1] += xs * w0.y; acc[2] += xs * w0.z; acc[3] += xs * w0.w;
        acc[4] += xs * w1.x; acc[5] += xs * w1.y; acc[6] += xs * w1.z; acc[7] += xs * w1.w;
      }
    }
#pragma unroll
    for (int off = 32; off >= 1; off >>= 1){
#pragma unroll
      for (int e = 0; e < 8; ++e) acc[e] += __shfl_xor(acc[e], off, 64);
    }
    if (lane == 0){
      float m = acc[0];
#pragma unroll
      for (int e = 1; e < 8; ++e) m = fmaxf(m, acc[e]);
      float p[8], s = 0.f;
#pragma unroll
      for (int e = 0; e < 8; ++e){ p[e] = __expf(acc[e] - m); s += p[e]; }
      float inv = 1.f / s;
#pragma unroll
      for (int e = 0; e < 8; ++e) psl[e] += p[e] * inv;
      int i1 = 0; float v1 = p[0];
#pragma unroll
      for (int e = 1; e < 8; ++e) if (p[e] > v1){ v1 = p[e]; i1 = e; }
      int i2 = -1; float v2 = -1.f;
#pragma unroll
      for (int e = 0; e < 8; ++e) if (e != i1 && p[e] > v2){ v2 = p[e]; i2 = e; }
      float rs = 1.f / (v1 + v2);
      topk_idx[2 * t] = i1; topk_idx[2 * t + 1] = i2;
      topk_w[2 * t] = v1 * rs; topk_w[2 * t + 1] = v2 * rs;
      histl[i1]++; histl[i2]++;
    }
  }
  if (lane == 0){
#pragma unroll
    for (int e = 0; e < 8; ++e){ hist_s[wv][e] = histl[e]; ps_s[wv][e] = psl[e]; }
  }
  __syncthreads();
  if (tid < 8){
    int hs = 0; float ps = 0.f;
#pragma unroll
    for (int w = 0; w < 4; ++w){ hs += hist_s[w][tid]; ps += ps_s[w][tid]; }
    partial_hist[blockIdx.x * 8 + tid]  = hs;
    partial_probs[blockIdx.x * 8 + tid] = ps;
  }
}

// ---------------- scan: padded bases + per-block offsets + aux loss ----------
__global__ void __launch_bounds__(64) scan_kernel(
    const int* __restrict__ partial_hist, const float* __restrict__ partial_probs,
    int* __restrict__ block_offset, float* __restrict__ out_aux)
{
  __shared__ int   csum[8][8];     // [chunk][expert], chunk = 64 blocks
  __shared__ float cps[8][8];
  __shared__ int   cbase[8][8];
  __shared__ int   base_s[8];
  int tid = threadIdx.x, e = tid & 7, c = tid >> 3;
  int s = 0; float f = 0.f;
  for (int b = c * 64; b < c * 64 + 64; ++b){
    s += partial_hist[b * 8 + e]; f += partial_probs[b * 8 + e];
  }
  csum[c][e] = s; cps[c][e] = f;
  __syncthreads();
  if (tid < 8){
    int tot = 0;
    for (int cc = 0; cc < 8; ++cc){ cbase[cc][tid] = tot; tot += csum[cc][tid]; }
    csum[0][tid] = tot;            // column total (cbase already captured)
  }
  __syncthreads();
  if (tid == 0){
    int off = 0;
    for (int ee = 0; ee < 8; ++ee){ base_s[ee] = off; off += (csum[0][ee] + 127) & ~127; }
    float a = 0.f;
    for (int ee = 0; ee < 8; ++ee){
      float ps = 0.f;
      for (int cc = 0; cc < 8; ++cc) ps += cps[cc][ee];
      float m = ps * (1.f / (float)T);
      a += m * m;
    }
    out_aux[0] = (float)E * a;
  }
  __syncthreads();
  int run = base_s[e] + cbase[c][e];
  for (int b = c * 64; b < c * 64 + 64; ++b){
    block_offset[b * 8 + e] = run;
    run += partial_hist[b * 8 + e];
  }
}

// ---------------- scatter: ballot-ranked, atomic-free ------------------------
// 512 blocks; block b covers pairs [b*32, b*32+32) (router block b's tokens)
__global__ void __launch_bounds__(64) scatter_kernel(
    const int* __restrict__ topk_idx, const float* __restrict__ topk_w,
    const int* __restrict__ block_offset,
    int* __restrict__ pair_token, int* __restrict__ pair_expert,
    float* __restrict__ pair_score)
{
  int lane = threadIdx.x, b = blockIdx.x;
  if (lane >= 32) return;
  int idx = b * 32 + lane;
  int t = idx >> 1;
  int e = topk_idx[idx];
  float w = topk_w[idx];
  unsigned long long below = lane ? ((1ull << lane) - 1ull) : 0ull;
  int rank = 0, basee = 0;
#pragma unroll
  for (int ee = 0; ee < 8; ++ee){
    unsigned long long m = __ballot(e == ee);
    if (e == ee){ rank = __popcll(m & below); basee = block_offset[b * 8 + ee]; }
  }
  int pos = basee + rank;
  pair_token[pos] = t;
  pair_expert[pos] = e;
  pair_score[pos] = w;
}

// ---------------- transposes: [R][C] f32 -> [C][R] bf16 ----------------------
__device__ __forceinline__ void transpose_body(const float* src, u16* dst, int R, int C,
                                               int bz){
  __shared__ float tile[32][33];
  long zoff = (long)bz * R * C;
  int tx = threadIdx.x & 31, ty = threadIdx.x >> 5;
  int c = blockIdx.x * 32 + tx;
  int rb = blockIdx.y * 32;
#pragma unroll
  for (int j = 0; j < 4; ++j)
    tile[ty + j * 8][tx] = src[zoff + (long)(rb + ty + j * 8) * C + c];
  __syncthreads();
#pragma unroll
  for (int j = 0; j < 4; ++j){
    int cc = blockIdx.x * 32 + ty + j * 8;
    dst[zoff + (long)cc * R + rb + tx] = f2bf(tile[tx][ty + j * 8]);
  }
}

__global__ void __launch_bounds__(256) transpose_kernel(const float* __restrict__ src,
                                                        u16* __restrict__ dst, int R, int C){
  transpose_body(src, dst, R, C, blockIdx.z);
}

__global__ void __launch_bounds__(256) transpose2_kernel(
    const float* __restrict__ s0, u16* __restrict__ d0,
    const float* __restrict__ s1, u16* __restrict__ d1, int R, int C, int Z){
  int z = blockIdx.z;
  if (z < Z) transpose_body(s0, d0, R, C, z);
  else       transpose_body(s1, d1, R, C, z - Z);
}

__global__ void __launch_bounds__(256) transpose3_kernel(
    const float* __restrict__ s0, u16* __restrict__ d0,
    const float* __restrict__ s1, u16* __restrict__ d1,
    const float* __restrict__ s2, u16* __restrict__ d2, int R, int C){
  int z = blockIdx.z;
  const float* s = (z == 0) ? s0 : (z == 1) ? s1 : s2;
  u16* d = (z == 0) ? d0 : (z == 1) ? d1 : d2;
  transpose_body(s, d, R, C, 0);
}

// ---------------- gate+up GEMM body (BM=128, BN=64, BK=64, dbuf) -------------
__device__ __forceinline__ void gateup_body(
    const u16* __restrict__ A, const u16* __restrict__ Bg, const u16* __restrict__ Bu,
    u16* __restrict__ Hout, int N, int K,
    const int* __restrict__ gather, int mtile, int ntile,
    u16 (*As)[128 * 64], u16 (*Bgs)[64 * 64], u16 (*Bus)[64 * 64])
{
  int tid = threadIdx.x, lane = tid & 63, wave = tid >> 6;
  int wy = wave >> 1, wx = wave & 1;
  int m0 = mtile * 128, n0 = ntile * 64;
  int rl = lane & 15, q = lane >> 4;

  StagePtr<4> spA; StagePtr<2> spG; StagePtr<2> spU;
  stage_init<128>(spA, A, K, m0, gather, wave, lane);
  stage_init<64>(spG, Bg, K, n0, nullptr, wave, lane);
  stage_init<64>(spU, Bu, K, n0, nullptr, wave, lane);

  f32x4 accG[4][2], accU[4][2];
#pragma unroll
  for (int i = 0; i < 4; ++i)
#pragma unroll
    for (int j = 0; j < 2; ++j)
#pragma unroll
      for (int r = 0; r < 4; ++r){ accG[i][j][r] = 0.f; accU[i][j][r] = 0.f; }

  stage_issue<128>(spA, 0, As[0], wave, lane);
  stage_issue<64>(spG, 0, Bgs[0], wave, lane);
  stage_issue<64>(spU, 0, Bus[0], wave, lane);

  int NI = K / 64;
  for (int i = 0; i < NI; ++i){
    int cur = i & 1, nxt = cur ^ 1;
    if (i + 1 < NI){
      int kn = (i + 1) * 64;
      stage_issue<128>(spA, kn, As[nxt], wave, lane);
      stage_issue<64>(spG, kn, Bgs[nxt], wave, lane);
      stage_issue<64>(spU, kn, Bus[nxt], wave, lane);
      wait_vmcnt8();               // cur tiles complete; nxt (8/wave) in flight
    } else {
      wait_vmcnt0();
    }
    bar_sync();
#pragma unroll
    for (int ks = 0; ks < 2; ++ks){
      int off = swz_off(ks * 4 + q, lane);
      short8 a[4], g2[2], u2[2];
#pragma unroll
      for (int mt = 0; mt < 4; ++mt)
        a[mt] = *(const short8*)(As[cur] + (wy * 64 + mt * 16 + rl) * 64 + off);
#pragma unroll
      for (int nt = 0; nt < 2; ++nt){
        g2[nt] = *(const short8*)(Bgs[cur] + (wx * 32 + nt * 16 + rl) * 64 + off);
        u2[nt] = *(const short8*)(Bus[cur] + (wx * 32 + nt * 16 + rl) * 64 + off);
      }
#pragma unroll
      for (int mt = 0; mt < 4; ++mt)
#pragma unroll
        for (int nt = 0; nt < 2; ++nt){
          accG[mt][nt] = __builtin_amdgcn_mfma_f32_16x16x32_bf16(a[mt], g2[nt], accG[mt][nt], 0, 0, 0);
          accU[mt][nt] = __builtin_amdgcn_mfma_f32_16x16x32_bf16(a[mt], u2[nt], accU[mt][nt], 0, 0, 0);
        }
    }
    if (i + 1 < NI) bar_sync();    // all waves done reading cur before overwrite
  }
  int row0 = m0 + wy * 64, col0 = n0 + wx * 32;
#pragma unroll
  for (int mt = 0; mt < 4; ++mt)
#pragma unroll
    for (int nt = 0; nt < 2; ++nt)
#pragma unroll
      for (int r = 0; r < 4; ++r){
        int row = row0 + mt * 16 + q * 4 + r;
        int col = col0 + nt * 16 + rl;
        float g = accG[mt][nt][r], u = accU[mt][nt][r];
        float h = g / (1.f + __expf(-g)) * u;
        Hout[(long)row * N + col] = f2bf(h);
      }
}

// fused: routed tiles (fid < 1088) + shared tiles
__global__ void __launch_bounds__(256) gateup_fused(
    const u16* __restrict__ xb,
    const u16* __restrict__ WgT, const u16* __restrict__ WuT, u16* __restrict__ hr,
    const u16* __restrict__ WsgT, const u16* __restrict__ WsuT, u16* __restrict__ hs,
    const int* __restrict__ pair_token, const int* __restrict__ pair_expert)
{
  __shared__ u16 As[2][128 * 64];
  __shared__ u16 Bgs[2][64 * 64];
  __shared__ u16 Bus[2][64 * 64];
  int fid = blockIdx.x;
  if (fid < GU_ROUTED_BLKS){
    int x8 = fid & 7, s = fid >> 3;              // s in [0,136)
    int mtile = x8 + 8 * (s >> 3), ntile = s & 7; // NT=8
    int e = pair_expert[mtile * 128];
    gateup_body(xb, WgT + (long)e * (D * H), WuT + (long)e * (D * H), hr,
                D, H, pair_token, mtile, ntile, As, Bgs, Bus);
  } else {
    int lid = fid - GU_ROUTED_BLKS;
    int x8 = lid & 7, s = lid >> 3;               // s in [0,128)
    int mtile = x8 + 8 * (s >> 4), ntile = s & 15; // NT=16
    gateup_body(xb, WsgT, WsuT, hs, DS, H, nullptr, mtile, ntile, As, Bgs, Bus);
  }
}

// ---------------- down GEMM body (BM=128, BN=128, BK=64, dbuf) ---------------
// ROUTED: unsafeAtomicAdd(score * val) scattered to out[token]; SHARED:
// unsafeAtomicAdd(val) to out[row]. out must be zeroed beforehand.
template<bool ROUTED>
__device__ __forceinline__ void down_body(
    const u16* __restrict__ A, const u16* __restrict__ B, int K,
    const float* __restrict__ pair_score, const int* __restrict__ pair_token,
    float* __restrict__ out, int mtile, int ntile,
    u16 (*As)[128 * 64], u16 (*Bs)[128 * 64])
{
  int tid = threadIdx.x, lane = tid & 63, wave = tid >> 6;
  int wy = wave >> 1, wx = wave & 1;
  int m0 = mtile * 128, n0 = ntile * 128;
  int rl = lane & 15, q = lane >> 4;

  StagePtr<4> spA, spB;
  stage_init<128>(spA, A, K, m0, nullptr, wave, lane);
  stage_init<128>(spB, B, K, n0, nullptr, wave, lane);

  f32x4 acc[4][4];
#pragma unroll
  for (int i = 0; i < 4; ++i)
#pragma unroll
    for (int j = 0; j < 4; ++j)
#pragma unroll
      for (int r = 0; r < 4; ++r) acc[i][j][r] = 0.f;

  stage_issue<128>(spA, 0, As[0], wave, lane);
  stage_issue<128>(spB, 0, Bs[0], wave, lane);

  int NI = K / 64;
  for (int i = 0; i < NI; ++i){
    int cur = i & 1, nxt = cur ^ 1;
    if (i + 1 < NI){
      int kn = (i + 1) * 64;
      stage_issue<128>(spA, kn, As[nxt], wave, lane);
      stage_issue<128>(spB, kn, Bs[nxt], wave, lane);
      wait_vmcnt8();
    } else {
      wait_vmcnt0();
    }
    bar_sync();
#pragma unroll
    for (int ks = 0; ks < 2; ++ks){
      int off = swz_off(ks * 4 + q, lane);
      short8 a[4], bv[4];
#pragma unroll
      for (int mt = 0; mt < 4; ++mt)
        a[mt] = *(const short8*)(As[cur] + (wy * 64 + mt * 16 + rl) * 64 + off);
#pragma unroll
      for (int nt = 0; nt < 4; ++nt)
        bv[nt] = *(const short8*)(Bs[cur] + (wx * 64 + nt * 16 + rl) * 64 + off);
#pragma unroll
      for (int mt = 0; mt < 4; ++mt)
#pragma unroll
        for (int nt = 0; nt < 4; ++nt)
          acc[mt][nt] = __builtin_amdgcn_mfma_f32_16x16x32_bf16(a[mt], bv[nt], acc[mt][nt], 0, 0, 0);
    }
    if (i + 1 < NI) bar_sync();
  }
#pragma unroll
  for (int mt = 0; mt < 4; ++mt)
#pragma unroll
    for (int r = 0; r < 4; ++r){
      int row = m0 + wy * 64 + mt * 16 + q * 4 + r;
      if (ROUTED){
        float s = pair_score[row];
        int tok = pair_token[row];
        float* o = out + (long)tok * H;
#pragma unroll
        for (int nt = 0; nt < 4; ++nt){
          int col = n0 + wx * 64 + nt * 16 + rl;
          unsafeAtomicAdd(o + col, s * acc[mt][nt][r]);
        }
      } else {
        float* o = out + (long)row * H;
#pragma unroll
        for (int nt = 0; nt < 4; ++nt){
          int col = n0 + wx * 64 + nt * 16 + rl;
          unsafeAtomicAdd(o + col, acc[mt][nt][r]);
        }
      }
    }
}

// fused: shared tiles first (2x K, start early), then routed tiles
__global__ void __launch_bounds__(256) down_fused(
    const u16* __restrict__ hs, const u16* __restrict__ WsdT,
    const u16* __restrict__ hr, const u16* __restrict__ WdT,
    const float* __restrict__ pair_score, const int* __restrict__ pair_token,
    const int* __restrict__ pair_expert, float* __restrict__ out)
{
  __shared__ u16 As[2][128 * 64];
  __shared__ u16 Bs[2][128 * 64];
  int fid = blockIdx.x;
  if (fid < DN_SHARED_BLKS){
    int x8 = fid & 7, s = fid >> 3;               // s in [0,64)
    int mtile = x8 + 8 * (s >> 3), ntile = s & 7;  // NT=8
    down_body<false>(hs, WsdT, DS, nullptr, nullptr, out, mtile, ntile, As, Bs);
  } else {
    int lid = fid - DN_SHARED_BLKS;
    int x8 = lid & 7, s = lid >> 3;               // s in [0,136)
    int mtile = x8 + 8 * (s >> 3), ntile = s & 7;  // NT=8
    int e = pair_expert[mtile * 128];
    down_body<true>(hr, WdT + (long)e * (H * D), D, pair_score, pair_token,
                    out, mtile, ntile, As, Bs);
  }
}

// ---------------- launch -----------------------------------------------------
extern "C" void kernel_launch(void* const* d_in, const int* in_sizes, int n_in,
                              void* d_out, int out_size, void* d_ws, size_t ws_size,
                              hipStream_t stream)
{
  (void)in_sizes; (void)n_in; (void)out_size; (void)ws_size;
  const float* x   = (const float*)d_in[0];
  const float* Wr  = (const float*)d_in[1];
  const float* Wg  = (const float*)d_in[2];
  const float* Wu  = (const float*)d_in[3];
  const float* Wd  = (const float*)d_in[4];
  const float* Wsg = (const float*)d_in[5];
  const float* Wsu = (const float*)d_in[6];
  const float* Wsd = (const float*)d_in[7];
  float* out = (float*)d_out;

  char* ws = (char*)d_ws;
  size_t off = 0;
  auto alloc = [&](size_t bytes) -> void* {
    void* p = ws + off; off += (bytes + 255) & ~(size_t)255; return p;
  };
  u16* xb   = (u16*)alloc((size_t)T * H * 2);
  u16* WsgT = (u16*)alloc((size_t)DS * H * 2);
  u16* WsuT = (u16*)alloc((size_t)DS * H * 2);
  u16* WsdT = (u16*)alloc((size_t)H * DS * 2);
  u16* WgT  = (u16*)alloc((size_t)E * D * H * 2);
  u16* WuT  = (u16*)alloc((size_t)E * D * H * 2);
  u16* WdT  = (u16*)alloc((size_t)E * H * D * 2);
  u16* hs   = (u16*)alloc((size_t)T * DS * 2);
  u16* hr   = (u16*)alloc((size_t)PAIR_CAP * D * 2);
  int*   topk_idx  = (int*)alloc((size_t)T * 2 * 4);
  float* topk_w    = (float*)alloc((size_t)T * 2 * 4);
  int*   partial_hist  = (int*)alloc((size_t)RB * 8 * 4);
  float* partial_probs = (float*)alloc((size_t)RB * 8 * 4);
  int*   block_offset  = (int*)alloc((size_t)RB * 8 * 4);
  // zero-initialized region (dummy pair slots must read as 0)
  char* zbase = ws + off;
  int*   pair_token  = (int*)alloc((size_t)PAIR_CAP * 4);
  int*   pair_expert = (int*)alloc((size_t)PAIR_CAP * 4);
  float* pair_score  = (float*)alloc((size_t)PAIR_CAP * 4);
  size_t zbytes = (size_t)((ws + off) - zbase);

  hipMemsetAsync(zbase, 0, zbytes, stream);
  hipMemsetAsync(out, 0, (size_t)T * H * 4, stream);   // atomic accumulate target

  // weight transposes (3 launches)
  transpose3_kernel<<<dim3(32, 32, 3), 256, 0, stream>>>(
      Wsg, WsgT, Wsu, WsuT, Wsd, WsdT, 1024, 1024);
  transpose2_kernel<<<dim3(D / 32, H / 32, 2 * E), 256, 0, stream>>>(
      Wg, WgT, Wu, WuT, H, D, E);
  transpose_kernel<<<dim3(H / 32, D / 32, E), 256, 0, stream>>>(Wd, WdT, D, H);

  router_kernel<<<RB, 256, 0, stream>>>(x, Wr, xb, topk_idx, topk_w,
                                        partial_hist, partial_probs);
  scan_kernel<<<1, 64, 0, stream>>>(partial_hist, partial_probs, block_offset,
                                    out + (size_t)T * H);
  scatter_kernel<<<RB, 64, 0, stream>>>(topk_idx, topk_w, block_offset,
                                        pair_token, pair_expert, pair_score);

  // fused gate+up: routed -> hr, shared -> hs (one launch)
  gateup_fused<<<GU_ROUTED_BLKS + GU_SHARED_BLKS, 256, 0, stream>>>(
      xb, WgT, WuT, hr, WsgT, WsuT, hs, pair_token, pair_expert);

  // fused down: shared + routed, atomic f32 combine into out (one launch)
  down_fused<<<DN_SHARED_BLKS + DN_ROUTED_BLKS, 256, 0, stream>>>(
      hs, WsdT, hr, WdT, pair_score, pair_token, pair_expert, out);
}

// Round 6
// 327.204 us; speedup vs baseline: 1.4162x; 1.4162x over previous
//
#include <hip/hip_runtime.h>

// MoE forward: shared SwiGLU expert + top-2/8 routed SwiGLU experts + aux loss.
// bf16 MFMA (16x16x32) GEMMs, 128-tile, global_load_lds width-16 staging.
// R1: atomic-free routing. R2: XOR chunk swizzle (0 LDS bank conflicts).
// R3/R4: dbuf LDS + raw s_barrier + vmcnt(8), XCD-aware tile remap.
// R5 FAILED: fp32 atomic combine -> 105MB RMW traffic, 205us down. R6 reverts
// to the R4 rout-buffer combine (non-atomic), keeps gateup fusion + single
// transpose launch.

typedef unsigned short u16;
typedef unsigned int   u32;
typedef short short8 __attribute__((ext_vector_type(8)));
typedef float f32x4  __attribute__((ext_vector_type(4)));

#define AS1 __attribute__((address_space(1)))
#define AS3 __attribute__((address_space(3)))

constexpr int T  = 8192;
constexpr int H  = 1024;
constexpr int E  = 8;
constexpr int D  = 512;
constexpr int DS = 1024;          // shared expert width
constexpr int PAIR_CAP  = 17408;  // 136 * 128 >= 16384 + 8*127
constexpr int MT_ROUTED = 136;    // routed m-tiles (128 rows each)
constexpr int RB = 512;           // router blocks (16 tokens each)

// grid splits for fused gate+up
constexpr int GU_ROUTED_BLKS = 8 * MT_ROUTED;   // 1088 (N=512 -> 8 n-tiles)
constexpr int GU_SHARED_BLKS = 16 * (T / 128);  // 1024 (N=1024 -> 16 n-tiles)

__device__ __forceinline__ u16 f2bf(float f){
  u32 u = __builtin_bit_cast(u32, f);
  u += 0x7fffu + ((u >> 16) & 1u);   // round-to-nearest-even
  return (u16)(u >> 16);
}
__device__ __forceinline__ float bf2f(u16 h){
  u32 u = ((u32)h) << 16;
  return __builtin_bit_cast(float, u);
}

// async global->LDS, 16B per lane. LDS dest = wave-uniform base + lane*16.
__device__ __forceinline__ void gl_lds16(const u16* g, u16* l){
  __builtin_amdgcn_global_load_lds((const AS1 void*)g, (AS3 void*)l, 16, 0, 0);
}

// s_waitcnt imm: vm[3:0] | exp=7<<4 | lgkm=15<<8 (vmcnt high bits 0)
__device__ __forceinline__ void wait_vmcnt8(){ __builtin_amdgcn_s_waitcnt(0x0f78); }
__device__ __forceinline__ void wait_vmcnt0(){ __builtin_amdgcn_s_waitcnt(0x0f70); }

// workgroup barrier with LDS-only ordering (no global vmcnt drain)
__device__ __forceinline__ void bar_sync(){
  __builtin_amdgcn_fence(__ATOMIC_RELEASE, "workgroup", "local");
  __builtin_amdgcn_s_barrier();
  __builtin_amdgcn_fence(__ATOMIC_ACQUIRE, "workgroup", "local");
}

// Per-wave staging pointers for a ROWS x 64(bf16) tile, XOR-swizzled:
// LDS slot (row, ch) holds global chunk (ch ^ (row&7)); swizzle applied on the
// per-lane GLOBAL source address (LDS dest must stay lane-ordered for
// global_load_lds). Row pointers precomputed once (gather loads hoisted).
template<int ISS>
struct StagePtr { const u16* p[ISS]; };

template<int ROWS>
__device__ __forceinline__ void stage_init(StagePtr<ROWS/32>& sp,
    const u16* __restrict__ gbase, int ld, int rowbase,
    const int* __restrict__ gather, int wave, int lane){
  constexpr int ISS = ROWS / 32;
  int lr = lane >> 3, ch = lane & 7;
  int chs = (ch ^ lr) * 8;         // swizzled source chunk offset (elems)
#pragma unroll
  for (int j = 0; j < ISS; ++j){
    int idx = wave * ISS + j;
    int row = idx * 8 + lr;
    int grow = gather ? gather[rowbase + row] : (rowbase + row);
    sp.p[j] = gbase + (long)grow * ld + chs;
  }
}

template<int ROWS>
__device__ __forceinline__ void stage_issue(const StagePtr<ROWS/32>& sp, int k0,
                                            u16* lds, int wave, int lane){
  constexpr int ISS = ROWS / 32;
#pragma unroll
  for (int j = 0; j < ISS; ++j)
    gl_lds16(sp.p[j] + k0, lds + (wave * ISS + j) * 512);
}

// Fragment read offset (elems) for logical chunk c at a row with row&7==lane&7.
__device__ __forceinline__ int swz_off(int c, int lane){
  return ((c ^ (lane & 7)) * 8);
}

// ---------------- router: logits -> softmax -> top2 + bf16 convert of x -----
// 512 blocks x 4 waves x 4 tokens. No global atomics. Also writes xb (bf16).
__global__ void __launch_bounds__(256) router_kernel(
    const float* __restrict__ x, const float* __restrict__ Wr,
    u16* __restrict__ xb,
    int* __restrict__ topk_idx, float* __restrict__ topk_w,
    int* __restrict__ partial_hist, float* __restrict__ partial_probs)
{
  __shared__ int   hist_s[4][8];
  __shared__ float ps_s[4][8];
  int tid = threadIdx.x, lane = tid & 63, wv = tid >> 6;
  int   histl[8] = {0,0,0,0,0,0,0,0};
  float psl[8]   = {0.f,0.f,0.f,0.f,0.f,0.f,0.f,0.f};

  for (int it = 0; it < 4; ++it){
    int t = blockIdx.x * 16 + wv * 4 + it;
    const float4* xr = (const float4*)(x + (long)t * H);
    uint2* xbr = (uint2*)(xb + (long)t * H);
    float acc[8];
#pragma unroll
    for (int e = 0; e < 8; ++e) acc[e] = 0.f;
#pragma unroll
    for (int i = 0; i < 4; ++i){
      float4 xv = xr[i * 64 + lane];
      u32 lo = (u32)f2bf(xv.x) | ((u32)f2bf(xv.y) << 16);
      u32 hi = (u32)f2bf(xv.z) | ((u32)f2bf(xv.w) << 16);
      xbr[i * 64 + lane] = make_uint2(lo, hi);
      int h0 = i * 256 + lane * 4;
#pragma unroll
      for (int j = 0; j < 4; ++j){
        float xs = (j == 0) ? xv.x : (j == 1) ? xv.y : (j == 2) ? xv.z : xv.w;
        const float4* wr = (const float4*)(Wr + (long)(h0 + j) * E);
        float4 w0 = wr[0], w1 = wr[1];
        acc[0] += xs * w0.x; acc[1] += xs * w0.y; acc[2] += xs * w0.z; acc[3] += xs * w0.w;
        acc[4] += xs * w1.x; acc[5] += xs * w1.y; acc[6] += xs * w1.z; acc[7] += xs * w1.w;
      }
    }
#pragma unroll
    for (int off = 32; off >= 1; off >>= 1){
#pragma unroll
      for (int e = 0; e < 8; ++e) acc[e] += __shfl_xor(acc[e], off, 64);
    }
    if (lane == 0){
      float m = acc[0];
#pragma unroll
      for (int e = 1; e < 8; ++e) m = fmaxf(m, acc[e]);
      float p[8], s = 0.f;
#pragma unroll
      for (int e = 0; e < 8; ++e){ p[e] = __expf(acc[e] - m); s += p[e]; }
      float inv = 1.f / s;
#pragma unroll
      for (int e = 0; e < 8; ++e) psl[e] += p[e] * inv;
      int i1 = 0; float v1 = p[0];
#pragma unroll
      for (int e = 1; e < 8; ++e) if (p[e] > v1){ v1 = p[e]; i1 = e; }
      int i2 = -1; float v2 = -1.f;
#pragma unroll
      for (int e = 0; e < 8; ++e) if (e != i1 && p[e] > v2){ v2 = p[e]; i2 = e; }
      float rs = 1.f / (v1 + v2);
      topk_idx[2 * t] = i1; topk_idx[2 * t + 1] = i2;
      topk_w[2 * t] = v1 * rs; topk_w[2 * t + 1] = v2 * rs;
      histl[i1]++; histl[i2]++;
    }
  }
  if (lane == 0){
#pragma unroll
    for (int e = 0; e < 8; ++e){ hist_s[wv][e] = histl[e]; ps_s[wv][e] = psl[e]; }
  }
  __syncthreads();
  if (tid < 8){
    int hs = 0; float ps = 0.f;
#pragma unroll
    for (int w = 0; w < 4; ++w){ hs += hist_s[w][tid]; ps += ps_s[w][tid]; }
    partial_hist[blockIdx.x * 8 + tid]  = hs;
    partial_probs[blockIdx.x * 8 + tid] = ps;
  }
}

// ---------------- scan: padded bases + per-block offsets + aux loss ----------
__global__ void __launch_bounds__(64) scan_kernel(
    const int* __restrict__ partial_hist, const float* __restrict__ partial_probs,
    int* __restrict__ block_offset, float* __restrict__ out_aux)
{
  __shared__ int   csum[8][8];     // [chunk][expert], chunk = 64 blocks
  __shared__ float cps[8][8];
  __shared__ int   cbase[8][8];
  __shared__ int   base_s[8];
  int tid = threadIdx.x, e = tid & 7, c = tid >> 3;
  int s = 0; float f = 0.f;
  for (int b = c * 64; b < c * 64 + 64; ++b){
    s += partial_hist[b * 8 + e]; f += partial_probs[b * 8 + e];
  }
  csum[c][e] = s; cps[c][e] = f;
  __syncthreads();
  if (tid < 8){
    int tot = 0;
    for (int cc = 0; cc < 8; ++cc){ cbase[cc][tid] = tot; tot += csum[cc][tid]; }
    csum[0][tid] = tot;            // column total (cbase already captured)
  }
  __syncthreads();
  if (tid == 0){
    int off = 0;
    for (int ee = 0; ee < 8; ++ee){ base_s[ee] = off; off += (csum[0][ee] + 127) & ~127; }
    float a = 0.f;
    for (int ee = 0; ee < 8; ++ee){
      float ps = 0.f;
      for (int cc = 0; cc < 8; ++cc) ps += cps[cc][ee];
      float m = ps * (1.f / (float)T);
      a += m * m;
    }
    out_aux[0] = (float)E * a;
  }
  __syncthreads();
  int run = base_s[e] + cbase[c][e];
  for (int b = c * 64; b < c * 64 + 64; ++b){
    block_offset[b * 8 + e] = run;
    run += partial_hist[b * 8 + e];
  }
}

// ---------------- scatter: ballot-ranked, atomic-free ------------------------
// 512 blocks; block b covers pairs [b*32, b*32+32) (router block b's tokens)
__global__ void __launch_bounds__(64) scatter_kernel(
    const int* __restrict__ topk_idx, const float* __restrict__ topk_w,
    const int* __restrict__ block_offset,
    int* __restrict__ pair_token, int* __restrict__ pair_expert,
    float* __restrict__ pair_score, int* __restrict__ token_pos)
{
  int lane = threadIdx.x, b = blockIdx.x;
  if (lane >= 32) return;
  int idx = b * 32 + lane;
  int t = idx >> 1;
  int e = topk_idx[idx];
  float w = topk_w[idx];
  unsigned long long below = lane ? ((1ull << lane) - 1ull) : 0ull;
  int rank = 0, basee = 0;
#pragma unroll
  for (int ee = 0; ee < 8; ++ee){
    unsigned long long m = __ballot(e == ee);
    if (e == ee){ rank = __popcll(m & below); basee = block_offset[b * 8 + ee]; }
  }
  int pos = basee + rank;
  pair_token[pos] = t;
  pair_expert[pos] = e;
  pair_score[pos] = w;
  token_pos[idx] = pos;
}

// ---------------- all weight transposes in ONE launch ------------------------
// z planes: [0,3) shared 1024x1024; [3,11) Wg, [11,19) Wu (1024x512);
// [19,27) Wd (512x1024). [R][C] f32 -> [C][R] bf16.
__global__ void __launch_bounds__(256) transpose_all(
    const float* __restrict__ Wsg, u16* __restrict__ WsgT,
    const float* __restrict__ Wsu, u16* __restrict__ WsuT,
    const float* __restrict__ Wsd, u16* __restrict__ WsdT,
    const float* __restrict__ Wg,  u16* __restrict__ WgT,
    const float* __restrict__ Wu,  u16* __restrict__ WuT,
    const float* __restrict__ Wd,  u16* __restrict__ WdT)
{
  __shared__ float tile[32][33];
  int z = blockIdx.z;
  const float* src; u16* dst; int R, C;
  if (z < 3){
    R = 1024; C = 1024;
    src = (z == 0) ? Wsg : (z == 1) ? Wsu : Wsd;
    dst = (z == 0) ? WsgT : (z == 1) ? WsuT : WsdT;
  } else if (z < 19){
    R = 1024; C = 512;
    int p = z - 3;
    if (p < 8){ src = Wg + (long)p * R * C; dst = WgT + (long)p * R * C; }
    else      { src = Wu + (long)(p - 8) * R * C; dst = WuT + (long)(p - 8) * R * C; }
  } else {
    R = 512; C = 1024;
    int p = z - 19;
    src = Wd + (long)p * R * C; dst = WdT + (long)p * R * C;
  }
  int tx = threadIdx.x & 31, ty = threadIdx.x >> 5;
  int c = blockIdx.x * 32 + tx;
  int rb = blockIdx.y * 32;
  if (blockIdx.x * 32 >= C || rb >= R) return;
#pragma unroll
  for (int j = 0; j < 4; ++j)
    tile[ty + j * 8][tx] = src[(long)(rb + ty + j * 8) * C + c];
  __syncthreads();
#pragma unroll
  for (int j = 0; j < 4; ++j){
    int cc = blockIdx.x * 32 + ty + j * 8;
    dst[(long)cc * R + rb + tx] = f2bf(tile[tx][ty + j * 8]);
  }
}

// ---------------- gate+up GEMM body (BM=128, BN=64, BK=64, dbuf) -------------
__device__ __forceinline__ void gateup_body(
    const u16* __restrict__ A, const u16* __restrict__ Bg, const u16* __restrict__ Bu,
    u16* __restrict__ Hout, int N, int K,
    const int* __restrict__ gather, int mtile, int ntile,
    u16 (*As)[128 * 64], u16 (*Bgs)[64 * 64], u16 (*Bus)[64 * 64])
{
  int tid = threadIdx.x, lane = tid & 63, wave = tid >> 6;
  int wy = wave >> 1, wx = wave & 1;
  int m0 = mtile * 128, n0 = ntile * 64;
  int rl = lane & 15, q = lane >> 4;

  StagePtr<4> spA; StagePtr<2> spG; StagePtr<2> spU;
  stage_init<128>(spA, A, K, m0, gather, wave, lane);
  stage_init<64>(spG, Bg, K, n0, nullptr, wave, lane);
  stage_init<64>(spU, Bu, K, n0, nullptr, wave, lane);

  f32x4 accG[4][2], accU[4][2];
#pragma unroll
  for (int i = 0; i < 4; ++i)
#pragma unroll
    for (int j = 0; j < 2; ++j)
#pragma unroll
      for (int r = 0; r < 4; ++r){ accG[i][j][r] = 0.f; accU[i][j][r] = 0.f; }

  stage_issue<128>(spA, 0, As[0], wave, lane);
  stage_issue<64>(spG, 0, Bgs[0], wave, lane);
  stage_issue<64>(spU, 0, Bus[0], wave, lane);

  int NI = K / 64;
  for (int i = 0; i < NI; ++i){
    int cur = i & 1, nxt = cur ^ 1;
    if (i + 1 < NI){
      int kn = (i + 1) * 64;
      stage_issue<128>(spA, kn, As[nxt], wave, lane);
      stage_issue<64>(spG, kn, Bgs[nxt], wave, lane);
      stage_issue<64>(spU, kn, Bus[nxt], wave, lane);
      wait_vmcnt8();               // cur tiles complete; nxt (8/wave) in flight
    } else {
      wait_vmcnt0();
    }
    bar_sync();
#pragma unroll
    for (int ks = 0; ks < 2; ++ks){
      int off = swz_off(ks * 4 + q, lane);
      short8 a[4], g2[2], u2[2];
#pragma unroll
      for (int mt = 0; mt < 4; ++mt)
        a[mt] = *(const short8*)(As[cur] + (wy * 64 + mt * 16 + rl) * 64 + off);
#pragma unroll
      for (int nt = 0; nt < 2; ++nt){
        g2[nt] = *(const short8*)(Bgs[cur] + (wx * 32 + nt * 16 + rl) * 64 + off);
        u2[nt] = *(const short8*)(Bus[cur] + (wx * 32 + nt * 16 + rl) * 64 + off);
      }
#pragma unroll
      for (int mt = 0; mt < 4; ++mt)
#pragma unroll
        for (int nt = 0; nt < 2; ++nt){
          accG[mt][nt] = __builtin_amdgcn_mfma_f32_16x16x32_bf16(a[mt], g2[nt], accG[mt][nt], 0, 0, 0);
          accU[mt][nt] = __builtin_amdgcn_mfma_f32_16x16x32_bf16(a[mt], u2[nt], accU[mt][nt], 0, 0, 0);
        }
    }
    if (i + 1 < NI) bar_sync();    // all waves done reading cur before overwrite
  }
  int row0 = m0 + wy * 64, col0 = n0 + wx * 32;
#pragma unroll
  for (int mt = 0; mt < 4; ++mt)
#pragma unroll
    for (int nt = 0; nt < 2; ++nt)
#pragma unroll
      for (int r = 0; r < 4; ++r){
        int row = row0 + mt * 16 + q * 4 + r;
        int col = col0 + nt * 16 + rl;
        float g = accG[mt][nt][r], u = accU[mt][nt][r];
        float h = g / (1.f + __expf(-g)) * u;
        Hout[(long)row * N + col] = f2bf(h);
      }
}

// fused: routed tiles (fid < 1088) + shared tiles
__global__ void __launch_bounds__(256) gateup_fused(
    const u16* __restrict__ xb,
    const u16* __restrict__ WgT, const u16* __restrict__ WuT, u16* __restrict__ hr,
    const u16* __restrict__ WsgT, const u16* __restrict__ WsuT, u16* __restrict__ hs,
    const int* __restrict__ pair_token, const int* __restrict__ pair_expert)
{
  __shared__ u16 As[2][128 * 64];
  __shared__ u16 Bgs[2][64 * 64];
  __shared__ u16 Bus[2][64 * 64];
  int fid = blockIdx.x;
  if (fid < GU_ROUTED_BLKS){
    int x8 = fid & 7, s = fid >> 3;               // s in [0,136)
    int mtile = x8 + 8 * (s >> 3), ntile = s & 7;  // NT=8
    int e = pair_expert[mtile * 128];
    gateup_body(xb, WgT + (long)e * (D * H), WuT + (long)e * (D * H), hr,
                D, H, pair_token, mtile, ntile, As, Bgs, Bus);
  } else {
    int lid = fid - GU_ROUTED_BLKS;
    int x8 = lid & 7, s = lid >> 3;                // s in [0,128)
    int mtile = x8 + 8 * (s >> 4), ntile = s & 15; // NT=16
    gateup_body(xb, WsgT, WsuT, hs, DS, H, nullptr, mtile, ntile, As, Bgs, Bus);
  }
}

// ---------------- down GEMM core: BM=128, BN=128, BK=64, dbuf (non-atomic) ---
// ROUTED: scale by pair_score, bf16 store to rout.
// SHARED: add routed rows via token_pos, fp32 store to out.
template<bool ROUTED>
__device__ __forceinline__ void down_body(
    const u16* __restrict__ A, const u16* __restrict__ B, int K,
    u16* __restrict__ rout, const float* __restrict__ pair_score,
    const int* __restrict__ token_pos, float* __restrict__ out,
    int mtile, int ntile, u16 (*As)[128 * 64], u16 (*Bs)[128 * 64])
{
  int tid = threadIdx.x, lane = tid & 63, wave = tid >> 6;
  int wy = wave >> 1, wx = wave & 1;
  int m0 = mtile * 128, n0 = ntile * 128;
  int rl = lane & 15, q = lane >> 4;

  StagePtr<4> spA, spB;
  stage_init<128>(spA, A, K, m0, nullptr, wave, lane);
  stage_init<128>(spB, B, K, n0, nullptr, wave, lane);

  f32x4 acc[4][4];
#pragma unroll
  for (int i = 0; i < 4; ++i)
#pragma unroll
    for (int j = 0; j < 4; ++j)
#pragma unroll
      for (int r = 0; r < 4; ++r) acc[i][j][r] = 0.f;

  stage_issue<128>(spA, 0, As[0], wave, lane);
  stage_issue<128>(spB, 0, Bs[0], wave, lane);

  int NI = K / 64;
  for (int i = 0; i < NI; ++i){
    int cur = i & 1, nxt = cur ^ 1;
    if (i + 1 < NI){
      int kn = (i + 1) * 64;
      stage_issue<128>(spA, kn, As[nxt], wave, lane);
      stage_issue<128>(spB, kn, Bs[nxt], wave, lane);
      wait_vmcnt8();
    } else {
      wait_vmcnt0();
    }
    bar_sync();
#pragma unroll
    for (int ks = 0; ks < 2; ++ks){
      int off = swz_off(ks * 4 + q, lane);
      short8 a[4], bv[4];
#pragma unroll
      for (int mt = 0; mt < 4; ++mt)
        a[mt] = *(const short8*)(As[cur] + (wy * 64 + mt * 16 + rl) * 64 + off);
#pragma unroll
      for (int nt = 0; nt < 4; ++nt)
        bv[nt] = *(const short8*)(Bs[cur] + (wx * 64 + nt * 16 + rl) * 64 + off);
#pragma unroll
      for (int mt = 0; mt < 4; ++mt)
#pragma unroll
        for (int nt = 0; nt < 4; ++nt)
          acc[mt][nt] = __builtin_amdgcn_mfma_f32_16x16x32_bf16(a[mt], bv[nt], acc[mt][nt], 0, 0, 0);
    }
    if (i + 1 < NI) bar_sync();
  }
#pragma unroll
  for (int mt = 0; mt < 4; ++mt)
#pragma unroll
    for (int r = 0; r < 4; ++r){
      int row = m0 + wy * 64 + mt * 16 + q * 4 + r;
      if (ROUTED){
        float s = pair_score[row];
        long rbase = (long)row * H;
#pragma unroll
        for (int nt = 0; nt < 4; ++nt){
          int col = n0 + wx * 64 + nt * 16 + rl;
          rout[rbase + col] = f2bf(s * acc[mt][nt][r]);
        }
      } else {
        int p0 = token_pos[2 * row], p1 = token_pos[2 * row + 1];
        long o = (long)row * H;
#pragma unroll
        for (int nt = 0; nt < 4; ++nt){
          int col = n0 + wx * 64 + nt * 16 + rl;
          out[o + col] = acc[mt][nt][r]
                       + bf2f(rout[(long)p0 * H + col])
                       + bf2f(rout[(long)p1 * H + col]);
        }
      }
    }
}

__global__ void __launch_bounds__(256) down_routed_kernel(
    const u16* __restrict__ A, const u16* __restrict__ B, u16* __restrict__ rout,
    const float* __restrict__ pair_score, const int* __restrict__ pexp)
{
  __shared__ u16 As[2][128 * 64];
  __shared__ u16 Bs[2][128 * 64];
  int fid = blockIdx.x;
  int x8 = fid & 7, s = fid >> 3;                // s in [0,136)
  int mtile = x8 + 8 * (s >> 3), ntile = s & 7;  // NT=8
  int e = pexp[mtile * 128];
  down_body<true>(A, B + (long)e * (H * D), D, rout, pair_score, nullptr,
                  nullptr, mtile, ntile, As, Bs);
}

__global__ void __launch_bounds__(256) down_shared_kernel(
    const u16* __restrict__ A, const u16* __restrict__ B,
    const u16* __restrict__ rout, const int* __restrict__ token_pos,
    float* __restrict__ out)
{
  __shared__ u16 As[2][128 * 64];
  __shared__ u16 Bs[2][128 * 64];
  int fid = blockIdx.x;
  int x8 = fid & 7, s = fid >> 3;                // s in [0,64)
  int mtile = x8 + 8 * (s >> 3), ntile = s & 7;  // NT=8
  down_body<false>(A, B, DS, const_cast<u16*>(rout), nullptr, token_pos, out,
                   mtile, ntile, As, Bs);
}

// ---------------- launch -----------------------------------------------------
extern "C" void kernel_launch(void* const* d_in, const int* in_sizes, int n_in,
                              void* d_out, int out_size, void* d_ws, size_t ws_size,
                              hipStream_t stream)
{
  (void)in_sizes; (void)n_in; (void)out_size; (void)ws_size;
  const float* x   = (const float*)d_in[0];
  const float* Wr  = (const float*)d_in[1];
  const float* Wg  = (const float*)d_in[2];
  const float* Wu  = (const float*)d_in[3];
  const float* Wd  = (const float*)d_in[4];
  const float* Wsg = (const float*)d_in[5];
  const float* Wsu = (const float*)d_in[6];
  const float* Wsd = (const float*)d_in[7];
  float* out = (float*)d_out;

  char* ws = (char*)d_ws;
  size_t off = 0;
  auto alloc = [&](size_t bytes) -> void* {
    void* p = ws + off; off += (bytes + 255) & ~(size_t)255; return p;
  };
  u16* xb   = (u16*)alloc((size_t)T * H * 2);
  u16* WsgT = (u16*)alloc((size_t)DS * H * 2);
  u16* WsuT = (u16*)alloc((size_t)DS * H * 2);
  u16* WsdT = (u16*)alloc((size_t)H * DS * 2);
  u16* WgT  = (u16*)alloc((size_t)E * D * H * 2);
  u16* WuT  = (u16*)alloc((size_t)E * D * H * 2);
  u16* WdT  = (u16*)alloc((size_t)E * H * D * 2);
  u16* hs   = (u16*)alloc((size_t)T * DS * 2);
  u16* hr   = (u16*)alloc((size_t)PAIR_CAP * D * 2);
  u16* rout = (u16*)alloc((size_t)PAIR_CAP * H * 2);
  int*   topk_idx  = (int*)alloc((size_t)T * 2 * 4);
  float* topk_w    = (float*)alloc((size_t)T * 2 * 4);
  int*   token_pos = (int*)alloc((size_t)T * 2 * 4);
  int*   partial_hist  = (int*)alloc((size_t)RB * 8 * 4);
  float* partial_probs = (float*)alloc((size_t)RB * 8 * 4);
  int*   block_offset  = (int*)alloc((size_t)RB * 8 * 4);
  // zero-initialized region (dummy pair slots must read as 0)
  char* zbase = ws + off;
  int*   pair_token  = (int*)alloc((size_t)PAIR_CAP * 4);
  int*   pair_expert = (int*)alloc((size_t)PAIR_CAP * 4);
  float* pair_score  = (float*)alloc((size_t)PAIR_CAP * 4);
  size_t zbytes = (size_t)((ws + off) - zbase);

  hipMemsetAsync(zbase, 0, zbytes, stream);

  // all weight transposes in one launch
  transpose_all<<<dim3(32, 32, 27), 256, 0, stream>>>(
      Wsg, WsgT, Wsu, WsuT, Wsd, WsdT, Wg, WgT, Wu, WuT, Wd, WdT);

  router_kernel<<<RB, 256, 0, stream>>>(x, Wr, xb, topk_idx, topk_w,
                                        partial_hist, partial_probs);
  scan_kernel<<<1, 64, 0, stream>>>(partial_hist, partial_probs, block_offset,
                                    out + (size_t)T * H);
  scatter_kernel<<<RB, 64, 0, stream>>>(topk_idx, topk_w, block_offset,
                                        pair_token, pair_expert, pair_score, token_pos);

  // fused gate+up: routed -> hr, shared -> hs (one launch)
  gateup_fused<<<GU_ROUTED_BLKS + GU_SHARED_BLKS, 256, 0, stream>>>(
      xb, WgT, WuT, hr, WsgT, WsuT, hs, pair_token, pair_expert);

  // routed down -> rout [PAIR_CAP x H], scaled by pair score (non-atomic)
  down_routed_kernel<<<8 * MT_ROUTED, 256, 0, stream>>>(
      hr, WdT, rout, pair_score, pair_expert);
  // shared down + combine -> out [T x H] fp32
  down_shared_kernel<<<8 * (T / 128), 256, 0, stream>>>(
      hs, WsdT, rout, token_pos, out);
}